// Round 3
// baseline (4455.825 us; speedup 1.0000x reference)
//
#include <hip/hip_runtime.h>
#include <hip/hip_bf16.h>

// Problem constants (Performer / FAVOR+ noncausal attention)
// ALL INPUTS AND THE OUTPUT ARE FLOAT32 (per reference). Intermediates bf16/f32.
#define B_   4
#define L_   4096
#define HID_ 1024
#define H_   16
#define DH_  64
#define M_   128
#define BL_  (B_*L_)        // 16384
#define NROW (BL_*H_)       // 262144

__device__ __forceinline__ float b2f(ushort s) {
    return __builtin_bit_cast(float, (unsigned int)s << 16);
}
__device__ __forceinline__ float bflo(unsigned int u) {
    return __builtin_bit_cast(float, u << 16);
}
__device__ __forceinline__ float bfhi(unsigned int u) {
    return __builtin_bit_cast(float, u & 0xffff0000u);
}
__device__ __forceinline__ ushort f2b(float f) {  // RNE
    unsigned int u = __builtin_bit_cast(unsigned int, f);
    u += 0x7fffu + ((u >> 16) & 1u);
    return (ushort)(u >> 16);
}

// ---------------------------------------------------------------------------
// GEMM A(f32)[MR,K] * W(f32)[K,N] -> C(bf16)[MR,N], fp32 accumulate.
// 64x64 tile, BK=16, 256 threads, 4x4 per thread.
// ---------------------------------------------------------------------------
__global__ __launch_bounds__(256) void gemm_f32_bf16(
    const float* __restrict__ A, const float* __restrict__ W,
    ushort* __restrict__ C, int MR, int N, int K)
{
    __shared__ float As[16][68];   // [k][m], padded
    __shared__ float Bs[16][68];   // [k][n], padded
    const int bm = blockIdx.y * 64, bn = blockIdx.x * 64;
    const int t  = threadIdx.x;
    const int tx = t & 15, ty = t >> 4;
    float acc[4][4] = {};

    for (int k0 = 0; k0 < K; k0 += 16) {
        {   // A tile: 64 rows x 16 k
            int r = t >> 2, c = (t & 3) * 4;
            float4 v = *(const float4*)(A + (size_t)(bm + r) * K + k0 + c);
            As[c+0][r] = v.x; As[c+1][r] = v.y; As[c+2][r] = v.z; As[c+3][r] = v.w;
        }
        {   // W tile: 16 k x 64 cols
            int r = t >> 4, c = (t & 15) * 4;
            float4 v = *(const float4*)(W + (size_t)(k0 + r) * N + bn + c);
            Bs[r][c+0] = v.x; Bs[r][c+1] = v.y; Bs[r][c+2] = v.z; Bs[r][c+3] = v.w;
        }
        __syncthreads();
        #pragma unroll
        for (int kk = 0; kk < 16; ++kk) {
            float4 av = *(const float4*)&As[kk][ty*4];
            float4 bv = *(const float4*)&Bs[kk][tx*4];
            acc[0][0] += av.x*bv.x; acc[0][1] += av.x*bv.y; acc[0][2] += av.x*bv.z; acc[0][3] += av.x*bv.w;
            acc[1][0] += av.y*bv.x; acc[1][1] += av.y*bv.y; acc[1][2] += av.y*bv.z; acc[1][3] += av.y*bv.w;
            acc[2][0] += av.z*bv.x; acc[2][1] += av.z*bv.y; acc[2][2] += av.z*bv.z; acc[2][3] += av.z*bv.w;
            acc[3][0] += av.w*bv.x; acc[3][1] += av.w*bv.y; acc[3][2] += av.w*bv.z; acc[3][3] += av.w*bv.w;
        }
        __syncthreads();
    }
    #pragma unroll
    for (int i = 0; i < 4; ++i) {
        ushort* crow = C + (size_t)(bm + ty*4 + i) * N + bn + tx*4;
        ushort4 st;
        st.x = f2b(acc[i][0]); st.y = f2b(acc[i][1]);
        st.z = f2b(acc[i][2]); st.w = f2b(acc[i][3]);
        *(ushort4*)crow = st;
    }
}

// ---------------------------------------------------------------------------
// GEMM A(bf16)[MR,K] * W(f32)[K,N] -> C(f32)[MR,N], fp32 accumulate.
// ---------------------------------------------------------------------------
__global__ __launch_bounds__(256) void gemm_bf16_f32(
    const ushort* __restrict__ A, const float* __restrict__ W,
    float* __restrict__ C, int MR, int N, int K)
{
    __shared__ float As[16][68];
    __shared__ float Bs[16][68];
    const int bm = blockIdx.y * 64, bn = blockIdx.x * 64;
    const int t  = threadIdx.x;
    const int tx = t & 15, ty = t >> 4;
    float acc[4][4] = {};

    for (int k0 = 0; k0 < K; k0 += 16) {
        {   // A tile (bf16): 64 rows x 16 k
            int r = t >> 2, c = (t & 3) * 4;
            ushort4 v = *(const ushort4*)(A + (size_t)(bm + r) * K + k0 + c);
            As[c+0][r] = b2f(v.x); As[c+1][r] = b2f(v.y);
            As[c+2][r] = b2f(v.z); As[c+3][r] = b2f(v.w);
        }
        {   // W tile (f32): 16 k x 64 cols
            int r = t >> 4, c = (t & 15) * 4;
            float4 v = *(const float4*)(W + (size_t)(k0 + r) * N + bn + c);
            Bs[r][c+0] = v.x; Bs[r][c+1] = v.y; Bs[r][c+2] = v.z; Bs[r][c+3] = v.w;
        }
        __syncthreads();
        #pragma unroll
        for (int kk = 0; kk < 16; ++kk) {
            float4 av = *(const float4*)&As[kk][ty*4];
            float4 bv = *(const float4*)&Bs[kk][tx*4];
            acc[0][0] += av.x*bv.x; acc[0][1] += av.x*bv.y; acc[0][2] += av.x*bv.z; acc[0][3] += av.x*bv.w;
            acc[1][0] += av.y*bv.x; acc[1][1] += av.y*bv.y; acc[1][2] += av.y*bv.z; acc[1][3] += av.y*bv.w;
            acc[2][0] += av.z*bv.x; acc[2][1] += av.z*bv.y; acc[2][2] += av.z*bv.z; acc[2][3] += av.z*bv.w;
            acc[3][0] += av.w*bv.x; acc[3][1] += av.w*bv.y; acc[3][2] += av.w*bv.z; acc[3][3] += av.w*bv.w;
        }
        __syncthreads();
    }
    #pragma unroll
    for (int i = 0; i < 4; ++i) {
        float* crow = C + (size_t)(bm + ty*4 + i) * N + bn + tx*4;
        *(float4*)crow = make_float4(acc[i][0], acc[i][1], acc[i][2], acc[i][3]);
    }
}

// ---------------------------------------------------------------------------
// phi: OUT[r,m] = relu(ratio * dot(X[r,:DH], proj[m,:DH])) + eps  -> bf16
// X bf16 [NROW, DH]; proj f32 [M, DH]; one block (128 thr = M) per row
// ---------------------------------------------------------------------------
__global__ __launch_bounds__(128) void phi_kernel(
    const ushort* __restrict__ X, const float* __restrict__ proj,
    ushort* __restrict__ OUT)
{
    __shared__ float xs[DH_];
    const int r = blockIdx.x;
    const int t = threadIdx.x;
    if (t < DH_) xs[t] = b2f(X[(size_t)r * DH_ + t]);
    __syncthreads();
    const float4* p4 = (const float4*)(proj + (size_t)t * DH_);
    float s = 0.f;
    #pragma unroll
    for (int i = 0; i < DH_/4; ++i) {
        float4 p = p4[i];
        s += p.x * xs[4*i] + p.y * xs[4*i+1] + p.z * xs[4*i+2] + p.w * xs[4*i+3];
    }
    s = fmaxf(s * 0.08838834764831845f, 0.f) + 1e-3f;
    OUT[(size_t)r * M_ + t] = f2b(s);
}

// ---------------------------------------------------------------------------
// kvs_part: partial KVS over a 512-long l-chunk, NO atomics, plain stores.
// KVSP[part][bh][m][65]: [0..63] = sum_l kp[l,m]*v[l,d]; [64] = sum_l kp[l,m]
// grid (B*H, 8); 256 threads; 48KB LDS (KP + V both bf16)
// ---------------------------------------------------------------------------
__global__ __launch_bounds__(256) void kvs_part_kernel(
    const ushort* __restrict__ KP, const ushort* __restrict__ V,
    float* __restrict__ KVSP)
{
    __shared__ ushort kps[128][128];   // [l][m] bf16, 32KB
    __shared__ ushort vsh[128][64];    // [l][d] bf16, 16KB
    const int bh = blockIdx.x;
    const int b = bh >> 4, h = bh & 15;
    const int t = threadIdx.x;
    const int m = t & 127, dg = t >> 7;   // dg uniform per wave
    float acc[32] = {};
    float accs = 0.f;

    for (int sub = 0; sub < 4; ++sub) {
        const int lbase = blockIdx.y * 512 + sub * 128;
        for (int i = t; i < 128*16; i += 256) {          // KP tile, uint4 units
            int l = i >> 4, pos = i & 15;
            size_t g = ((size_t)(b*L_ + lbase + l) * H_ + h) * M_ + pos*8;
            *(uint4*)&kps[l][pos*8] = *(const uint4*)&KP[g];
        }
        for (int i = t; i < 128*8; i += 256) {           // V tile (bf16)
            int l = i >> 3, pos = i & 7;
            size_t g = ((size_t)(b*L_ + lbase + l) * H_ + h) * DH_ + pos*8;
            *(uint4*)&vsh[l][pos*8] = *(const uint4*)&V[g];
        }
        __syncthreads();
        for (int l = 0; l < 128; ++l) {
            float kp = b2f(kps[l][m]);
            if (dg == 0) accs += kp;
            const unsigned int* vr = (const unsigned int*)&vsh[l][dg*32];
            #pragma unroll
            for (int j = 0; j < 16; ++j) {
                unsigned int u = vr[j];
                acc[2*j]   += kp * bflo(u);
                acc[2*j+1] += kp * bfhi(u);
            }
        }
        __syncthreads();
    }
    float* dst = KVSP + ((size_t)(blockIdx.y * 64 + bh) * M_ + m) * 65;
    #pragma unroll
    for (int j = 0; j < 32; ++j) dst[dg*32 + j] = acc[j];
    if (dg == 0) dst[64] = accs;
}

// ---------------------------------------------------------------------------
// kvs_reduce: KVS[bh][m][c] = sum_{p<8} KVSP[p][bh][m][c]
// ---------------------------------------------------------------------------
__global__ __launch_bounds__(256) void kvs_reduce_kernel(
    const float* __restrict__ KVSP, float* __restrict__ KVS)
{
    const int bh = blockIdx.x;
    for (int i = threadIdx.x; i < M_*65; i += 256) {
        float s = 0.f;
        #pragma unroll
        for (int p = 0; p < 8; ++p)
            s += KVSP[(size_t)(p*64 + bh) * (M_*65) + i];
        KVS[(size_t)bh * (M_*65) + i] = s;
    }
}

// ---------------------------------------------------------------------------
// num: NUM[r,d] = sum_m qp[r,m]*KVS[bh][m][d], kvs resident in LDS
// grid (B*H, L/64); 256 threads = (l 0..63) x (dg 0..3, 16 d each)
// ---------------------------------------------------------------------------
__global__ __launch_bounds__(256) void num_kernel(
    const ushort* __restrict__ QP, const float* __restrict__ KVS,
    float* __restrict__ NUM)
{
    __shared__ ushort qps[64][130];    // [l][m], padded
    __shared__ float  kvf[128][64];    // [m][d]
    const int bh = blockIdx.x;
    const int b = bh >> 4, h = bh & 15;
    const int l0 = blockIdx.y * 64;
    const int t = threadIdx.x;

    for (int i = t; i < 128*64; i += 256) {
        int mm = i >> 6, c = i & 63;
        kvf[mm][c] = KVS[((size_t)bh * M_ + mm) * 65 + c];
    }
    for (int i = t; i < 64*16; i += 256) {      // qp tile, uint4 units
        int l = i >> 4, pos = i & 15;
        size_t g = ((size_t)(b*L_ + l0 + l) * H_ + h) * M_ + pos*8;
        uint4 v = *(const uint4*)&QP[g];
        ushort* d = &qps[l][pos*8];
        d[0]=(ushort)(v.x & 0xffff); d[1]=(ushort)(v.x >> 16);
        d[2]=(ushort)(v.y & 0xffff); d[3]=(ushort)(v.y >> 16);
        d[4]=(ushort)(v.z & 0xffff); d[5]=(ushort)(v.z >> 16);
        d[6]=(ushort)(v.w & 0xffff); d[7]=(ushort)(v.w >> 16);
    }
    __syncthreads();

    const int l = t & 63, dg = t >> 6;
    const int dbase = dg * 16;
    float acc[16] = {};
    for (int mm = 0; mm < 128; ++mm) {
        float q = b2f(qps[l][mm]);
        const float* kr = &kvf[mm][dbase];
        #pragma unroll
        for (int jj = 0; jj < 4; ++jj) {
            float4 v4 = *(const float4*)&kr[jj*4];
            acc[jj*4+0] += q*v4.x; acc[jj*4+1] += q*v4.y;
            acc[jj*4+2] += q*v4.z; acc[jj*4+3] += q*v4.w;
        }
    }
    size_t r = (size_t)(b*L_ + l0 + l) * H_ + h;
    float* o = NUM + r * DH_ + dbase;
    #pragma unroll
    for (int jj = 0; jj < 4; ++jj) {
        *(float4*)&o[jj*4] = make_float4(acc[jj*4+0], acc[jj*4+1], acc[jj*4+2], acc[jj*4+3]);
    }
}

// ---------------------------------------------------------------------------
// att_finish: den[r] = dot(qp[r,:], ks[:]);  ATT[r,d] = NUM[r,d]/den -> bf16
// one wave per row; grid NROW/4, 256 threads
// ---------------------------------------------------------------------------
__global__ __launch_bounds__(256) void att_finish(
    const float* __restrict__ NUM, const ushort* __restrict__ QP,
    const float* __restrict__ KVS, ushort* __restrict__ ATT)
{
    const int t = threadIdx.x;
    const int r = blockIdx.x * 4 + (t >> 6);
    const int lane = t & 63;
    const int b = r >> 16;       // r = b*65536 + l*16 + h
    const int h = r & 15;
    const int bh = (b << 4) | h;

    unsigned int u = *(const unsigned int*)(QP + (size_t)r * M_ + 2*lane);
    const float* ksb = KVS + (size_t)bh * M_ * 65 + 64;
    float den = bflo(u) * ksb[(size_t)(2*lane) * 65]
              + bfhi(u) * ksb[(size_t)(2*lane+1) * 65];
    #pragma unroll
    for (int off = 32; off > 0; off >>= 1) den += __shfl_xor(den, off, 64);
    den = fmaxf(den, 1e-10f);   // no-op when correct (den >= ~0.5)

    float nv = NUM[(size_t)r * DH_ + lane];
    ATT[(size_t)r * DH_ + lane] = f2b(nv / den);
}

// ---------------------------------------------------------------------------
extern "C" void kernel_launch(void* const* d_in, const int* in_sizes, int n_in,
                              void* d_out, int out_size, void* d_ws, size_t ws_size,
                              hipStream_t stream)
{
    const float* Xq = (const float*)d_in[0];   // [B,L,HID] f32
    const float* Xs = (const float*)d_in[1];   // [B,L,HID] f32
    const float* Wq = (const float*)d_in[2];   // [HID,H,DH] f32
    const float* Wk = (const float*)d_in[3];
    const float* Wv = (const float*)d_in[4];
    const float* Wo = (const float*)d_in[5];   // [H,DH,HID] f32
    const float* Pj = (const float*)d_in[6];   // [M,DH] f32
    float* out = (float*)d_out;                // [B,L,HID] f32

    char* ws = (char*)d_ws;
    ushort* Qb  = (ushort*)(ws + 0);            // 32MB (Q bf16; later KVSP; later ATT)
    ushort* Kb  = (ushort*)(ws + 33554432);     // 32MB (K bf16)
    ushort* Vb  = (ushort*)(ws + 67108864);     // 32MB (V bf16)
    ushort* QPb = (ushort*)(ws + 100663296);    // 64MB (QP bf16)
    ushort* KPb = (ushort*)(ws + 167772160);    // 64MB (KP bf16; later NUM f32)
    float*  KVS = (float*)(ws + 234881024);     // ~2.1MB f32
    float*  KVSP = (float*)(ws + 0);            // 17MB, alias Q (dead after phi)
    float*  NUM = (float*)(ws + 167772160);     // alias KP (dead after kvs)
    ushort* ATT = Qb;                           // alias Q/KVSP (dead after reduce)

    dim3 tb(256);
    dim3 gG(HID_/64, BL_/64);   // 16 x 256

    gemm_f32_bf16<<<gG, tb, 0, stream>>>(Xq, Wq, Qb, BL_, HID_, HID_);
    gemm_f32_bf16<<<gG, tb, 0, stream>>>(Xs, Wk, Kb, BL_, HID_, HID_);
    gemm_f32_bf16<<<gG, tb, 0, stream>>>(Xs, Wv, Vb, BL_, HID_, HID_);

    phi_kernel<<<NROW, 128, 0, stream>>>(Qb, Pj, QPb);
    phi_kernel<<<NROW, 128, 0, stream>>>(Kb, Pj, KPb);

    kvs_part_kernel<<<dim3(B_*H_, 8), tb, 0, stream>>>(KPb, Vb, KVSP);
    kvs_reduce_kernel<<<B_*H_, tb, 0, stream>>>(KVSP, KVS);

    num_kernel<<<dim3(B_*H_, L_/64), tb, 0, stream>>>(QPb, KVS, NUM);
    att_finish<<<NROW/4, tb, 0, stream>>>(NUM, QPb, KVS, ATT);

    gemm_bf16_f32<<<gG, tb, 0, stream>>>(ATT, Wo, out, BL_, HID_, HID_);
    (void)in_sizes; (void)n_in; (void)out_size; (void)ws_size;
}

// Round 4
// 2802.753 us; speedup vs baseline: 1.5898x; 1.5898x over previous
//
#include <hip/hip_runtime.h>
#include <hip/hip_bf16.h>

// Performer / FAVOR+ noncausal attention. ALL inputs + output are FLOAT32.
// Intermediates bf16/f32.
#define B_   4
#define L_   4096
#define HID_ 1024
#define H_   16
#define DH_  64
#define M_   128
#define BL_  (B_*L_)        // 16384
#define NROW (BL_*H_)       // 262144

__device__ __forceinline__ float b2f(ushort s) {
    return __builtin_bit_cast(float, (unsigned int)s << 16);
}
__device__ __forceinline__ float bflo(unsigned int u) {
    return __builtin_bit_cast(float, u << 16);
}
__device__ __forceinline__ float bfhi(unsigned int u) {
    return __builtin_bit_cast(float, u & 0xffff0000u);
}
__device__ __forceinline__ ushort f2b(float f) {  // RNE
    unsigned int u = __builtin_bit_cast(unsigned int, f);
    u += 0x7fffu + ((u >> 16) & 1u);
    return (ushort)(u >> 16);
}

// ---------------------------------------------------------------------------
// Fused QK projection + phi:
//   q[64x64] = A_tile[64,1024] x W[:, h*64..h*64+63]   (f32 acc)
//   QP[row, h, m] = relu(ratio * dot(q[row,:], proj[m,:])) + eps   (bf16)
// grid (H, BL/64), 256 threads.
// ---------------------------------------------------------------------------
__global__ __launch_bounds__(256) void gemm_phi(
    const float* __restrict__ A, const float* __restrict__ W,
    const float* __restrict__ proj, ushort* __restrict__ OUT)
{
    __shared__ float As[16][68];        // [k][m], padded
    __shared__ float Bs[16][68];        // [k][n], padded
    __shared__ float pjs[M_][DH_];      // [m][k] XOR-swizzled in k-quads
    __shared__ float qs[64][68];        // q tile f32, padded
    const int h  = blockIdx.x;
    const int bm = blockIdx.y * 64, bn = h * 64;
    const int t  = threadIdx.x;
    const int tx = t & 15, ty = t >> 4;
    float acc[4][4] = {};

    // stage proj: 128x64 f32, store k-quad kq at position (kq ^ (m>>3))
    for (int i = t; i < M_*DH_/4; i += 256) {
        int m = i >> 4, kq = i & 15;
        float4 v = *(const float4*)(proj + (size_t)m * DH_ + kq * 4);
        *(float4*)&pjs[m][((kq ^ (m >> 3)) & 15) * 4] = v;
    }

    for (int k0 = 0; k0 < HID_; k0 += 16) {
        {   // A tile: 64 rows x 16 k
            int r = t >> 2, c = (t & 3) * 4;
            float4 v = *(const float4*)(A + (size_t)(bm + r) * HID_ + k0 + c);
            As[c+0][r] = v.x; As[c+1][r] = v.y; As[c+2][r] = v.z; As[c+3][r] = v.w;
        }
        {   // W tile: 16 k x 64 cols
            int r = t >> 4, c = (t & 15) * 4;
            float4 v = *(const float4*)(W + (size_t)(k0 + r) * HID_ + bn + c);
            Bs[r][c+0] = v.x; Bs[r][c+1] = v.y; Bs[r][c+2] = v.z; Bs[r][c+3] = v.w;
        }
        __syncthreads();
        #pragma unroll
        for (int kk = 0; kk < 16; ++kk) {
            float4 av = *(const float4*)&As[kk][ty*4];
            float4 bv = *(const float4*)&Bs[kk][tx*4];
            acc[0][0] += av.x*bv.x; acc[0][1] += av.x*bv.y; acc[0][2] += av.x*bv.z; acc[0][3] += av.x*bv.w;
            acc[1][0] += av.y*bv.x; acc[1][1] += av.y*bv.y; acc[1][2] += av.y*bv.z; acc[1][3] += av.y*bv.w;
            acc[2][0] += av.z*bv.x; acc[2][1] += av.z*bv.y; acc[2][2] += av.z*bv.z; acc[2][3] += av.z*bv.w;
            acc[3][0] += av.w*bv.x; acc[3][1] += av.w*bv.y; acc[3][2] += av.w*bv.z; acc[3][3] += av.w*bv.w;
        }
        __syncthreads();
    }

    // ---- phi epilogue: stage q tile, then 64x128 = qs[64,64] x proj^T ----
    #pragma unroll
    for (int i = 0; i < 4; ++i) {
        qs[ty*4+i][tx*4+0] = acc[i][0];
        qs[ty*4+i][tx*4+1] = acc[i][1];
        qs[ty*4+i][tx*4+2] = acc[i][2];
        qs[ty*4+i][tx*4+3] = acc[i][3];
    }
    __syncthreads();

    float o[4][8] = {};
    #pragma unroll
    for (int kq = 0; kq < 16; ++kq) {
        float4 q0 = *(const float4*)&qs[ty*4+0][kq*4];
        float4 q1 = *(const float4*)&qs[ty*4+1][kq*4];
        float4 q2 = *(const float4*)&qs[ty*4+2][kq*4];
        float4 q3 = *(const float4*)&qs[ty*4+3][kq*4];
        #pragma unroll
        for (int jm = 0; jm < 8; ++jm) {
            // m = tx*8+jm -> m>>3 == tx; stored quad index = kq ^ tx
            float4 p = *(const float4*)&pjs[tx*8+jm][((kq ^ tx) & 15) * 4];
            o[0][jm] += q0.x*p.x + q0.y*p.y + q0.z*p.z + q0.w*p.w;
            o[1][jm] += q1.x*p.x + q1.y*p.y + q1.z*p.z + q1.w*p.w;
            o[2][jm] += q2.x*p.x + q2.y*p.y + q2.z*p.z + q2.w*p.w;
            o[3][jm] += q3.x*p.x + q3.y*p.y + q3.z*p.z + q3.w*p.w;
        }
    }

    const float ratio = 0.08838834764831845f;
    #pragma unroll
    for (int i = 0; i < 4; ++i) {
        unsigned int w[4];
        #pragma unroll
        for (int jp = 0; jp < 4; ++jp) {
            float a0 = fmaxf(o[i][2*jp+0] * ratio, 0.f) + 1e-3f;
            float a1 = fmaxf(o[i][2*jp+1] * ratio, 0.f) + 1e-3f;
            w[jp] = (unsigned int)f2b(a0) | ((unsigned int)f2b(a1) << 16);
        }
        size_t r = (size_t)(bm + ty*4 + i);
        *(uint4*)&OUT[(r * H_ + h) * M_ + tx*8] =
            make_uint4(w[0], w[1], w[2], w[3]);
    }
}

// ---------------------------------------------------------------------------
// GEMM A(f32)[MR,K] * W(f32)[K,N] -> C(bf16)[MR,N], fp32 accumulate. (V proj)
// ---------------------------------------------------------------------------
__global__ __launch_bounds__(256) void gemm_f32_bf16(
    const float* __restrict__ A, const float* __restrict__ W,
    ushort* __restrict__ C, int MR, int N, int K)
{
    __shared__ float As[16][68];
    __shared__ float Bs[16][68];
    const int bm = blockIdx.y * 64, bn = blockIdx.x * 64;
    const int t  = threadIdx.x;
    const int tx = t & 15, ty = t >> 4;
    float acc[4][4] = {};

    for (int k0 = 0; k0 < K; k0 += 16) {
        {
            int r = t >> 2, c = (t & 3) * 4;
            float4 v = *(const float4*)(A + (size_t)(bm + r) * K + k0 + c);
            As[c+0][r] = v.x; As[c+1][r] = v.y; As[c+2][r] = v.z; As[c+3][r] = v.w;
        }
        {
            int r = t >> 4, c = (t & 15) * 4;
            float4 v = *(const float4*)(W + (size_t)(k0 + r) * N + bn + c);
            Bs[r][c+0] = v.x; Bs[r][c+1] = v.y; Bs[r][c+2] = v.z; Bs[r][c+3] = v.w;
        }
        __syncthreads();
        #pragma unroll
        for (int kk = 0; kk < 16; ++kk) {
            float4 av = *(const float4*)&As[kk][ty*4];
            float4 bv = *(const float4*)&Bs[kk][tx*4];
            acc[0][0] += av.x*bv.x; acc[0][1] += av.x*bv.y; acc[0][2] += av.x*bv.z; acc[0][3] += av.x*bv.w;
            acc[1][0] += av.y*bv.x; acc[1][1] += av.y*bv.y; acc[1][2] += av.y*bv.z; acc[1][3] += av.y*bv.w;
            acc[2][0] += av.z*bv.x; acc[2][1] += av.z*bv.y; acc[2][2] += av.z*bv.z; acc[2][3] += av.z*bv.w;
            acc[3][0] += av.w*bv.x; acc[3][1] += av.w*bv.y; acc[3][2] += av.w*bv.z; acc[3][3] += av.w*bv.w;
        }
        __syncthreads();
    }
    #pragma unroll
    for (int i = 0; i < 4; ++i) {
        ushort* crow = C + (size_t)(bm + ty*4 + i) * N + bn + tx*4;
        ushort4 st;
        st.x = f2b(acc[i][0]); st.y = f2b(acc[i][1]);
        st.z = f2b(acc[i][2]); st.w = f2b(acc[i][3]);
        *(ushort4*)crow = st;
    }
}

// ---------------------------------------------------------------------------
// GEMM A(bf16)[MR,K] * W(f32)[K,N] -> C(f32)[MR,N], fp32 accumulate. (out proj)
// ---------------------------------------------------------------------------
__global__ __launch_bounds__(256) void gemm_bf16_f32(
    const ushort* __restrict__ A, const float* __restrict__ W,
    float* __restrict__ C, int MR, int N, int K)
{
    __shared__ float As[16][68];
    __shared__ float Bs[16][68];
    const int bm = blockIdx.y * 64, bn = blockIdx.x * 64;
    const int t  = threadIdx.x;
    const int tx = t & 15, ty = t >> 4;
    float acc[4][4] = {};

    for (int k0 = 0; k0 < K; k0 += 16) {
        {
            int r = t >> 2, c = (t & 3) * 4;
            ushort4 v = *(const ushort4*)(A + (size_t)(bm + r) * K + k0 + c);
            As[c+0][r] = b2f(v.x); As[c+1][r] = b2f(v.y);
            As[c+2][r] = b2f(v.z); As[c+3][r] = b2f(v.w);
        }
        {
            int r = t >> 4, c = (t & 15) * 4;
            float4 v = *(const float4*)(W + (size_t)(k0 + r) * N + bn + c);
            Bs[r][c+0] = v.x; Bs[r][c+1] = v.y; Bs[r][c+2] = v.z; Bs[r][c+3] = v.w;
        }
        __syncthreads();
        #pragma unroll
        for (int kk = 0; kk < 16; ++kk) {
            float4 av = *(const float4*)&As[kk][ty*4];
            float4 bv = *(const float4*)&Bs[kk][tx*4];
            acc[0][0] += av.x*bv.x; acc[0][1] += av.x*bv.y; acc[0][2] += av.x*bv.z; acc[0][3] += av.x*bv.w;
            acc[1][0] += av.y*bv.x; acc[1][1] += av.y*bv.y; acc[1][2] += av.y*bv.z; acc[1][3] += av.y*bv.w;
            acc[2][0] += av.z*bv.x; acc[2][1] += av.z*bv.y; acc[2][2] += av.z*bv.z; acc[2][3] += av.z*bv.w;
            acc[3][0] += av.w*bv.x; acc[3][1] += av.w*bv.y; acc[3][2] += av.w*bv.z; acc[3][3] += av.w*bv.w;
        }
        __syncthreads();
    }
    #pragma unroll
    for (int i = 0; i < 4; ++i) {
        float* crow = C + (size_t)(bm + ty*4 + i) * N + bn + tx*4;
        *(float4*)crow = make_float4(acc[i][0], acc[i][1], acc[i][2], acc[i][3]);
    }
}

// ---------------------------------------------------------------------------
// kvs_part: partial KVS over a 512-long l-chunk, plain stores (no atomics).
// KVSP[part][bh][m][65]: [0..63] = sum_l kp[l,m]*v[l,d]; [64] = sum_l kp[l,m]
// ---------------------------------------------------------------------------
__global__ __launch_bounds__(256) void kvs_part_kernel(
    const ushort* __restrict__ KP, const ushort* __restrict__ V,
    float* __restrict__ KVSP)
{
    __shared__ ushort kps[128][128];
    __shared__ ushort vsh[128][64];
    const int bh = blockIdx.x;
    const int b = bh >> 4, h = bh & 15;
    const int t = threadIdx.x;
    const int m = t & 127, dg = t >> 7;
    float acc[32] = {};
    float accs = 0.f;

    for (int sub = 0; sub < 4; ++sub) {
        const int lbase = blockIdx.y * 512 + sub * 128;
        for (int i = t; i < 128*16; i += 256) {
            int l = i >> 4, pos = i & 15;
            size_t g = ((size_t)(b*L_ + lbase + l) * H_ + h) * M_ + pos*8;
            *(uint4*)&kps[l][pos*8] = *(const uint4*)&KP[g];
        }
        for (int i = t; i < 128*8; i += 256) {
            int l = i >> 3, pos = i & 7;
            size_t g = ((size_t)(b*L_ + lbase + l) * H_ + h) * DH_ + pos*8;
            *(uint4*)&vsh[l][pos*8] = *(const uint4*)&V[g];
        }
        __syncthreads();
        for (int l = 0; l < 128; ++l) {
            float kp = b2f(kps[l][m]);
            if (dg == 0) accs += kp;
            const unsigned int* vr = (const unsigned int*)&vsh[l][dg*32];
            #pragma unroll
            for (int j = 0; j < 16; ++j) {
                unsigned int u = vr[j];
                acc[2*j]   += kp * bflo(u);
                acc[2*j+1] += kp * bfhi(u);
            }
        }
        __syncthreads();
    }
    float* dst = KVSP + ((size_t)(blockIdx.y * 64 + bh) * M_ + m) * 65;
    #pragma unroll
    for (int j = 0; j < 32; ++j) dst[dg*32 + j] = acc[j];
    if (dg == 0) dst[64] = accs;
}

__global__ __launch_bounds__(256) void kvs_reduce_kernel(
    const float* __restrict__ KVSP, float* __restrict__ KVS)
{
    const int bh = blockIdx.x;
    for (int i = threadIdx.x; i < M_*65; i += 256) {
        float s = 0.f;
        #pragma unroll
        for (int p = 0; p < 8; ++p)
            s += KVSP[(size_t)(p*64 + bh) * (M_*65) + i];
        KVS[(size_t)bh * (M_*65) + i] = s;
    }
}

// ---------------------------------------------------------------------------
// num: NUM[r,d] = sum_m qp[r,m]*KVS[bh][m][d], kvs resident in LDS
// ---------------------------------------------------------------------------
__global__ __launch_bounds__(256) void num_kernel(
    const ushort* __restrict__ QP, const float* __restrict__ KVS,
    float* __restrict__ NUM)
{
    __shared__ ushort qps[64][130];
    __shared__ float  kvf[128][64];
    const int bh = blockIdx.x;
    const int b = bh >> 4, h = bh & 15;
    const int l0 = blockIdx.y * 64;
    const int t = threadIdx.x;

    for (int i = t; i < 128*64; i += 256) {
        int mm = i >> 6, c = i & 63;
        kvf[mm][c] = KVS[((size_t)bh * M_ + mm) * 65 + c];
    }
    for (int i = t; i < 64*16; i += 256) {
        int l = i >> 4, pos = i & 15;
        size_t g = ((size_t)(b*L_ + l0 + l) * H_ + h) * M_ + pos*8;
        uint4 v = *(const uint4*)&QP[g];
        ushort* d = &qps[l][pos*8];
        d[0]=(ushort)(v.x & 0xffff); d[1]=(ushort)(v.x >> 16);
        d[2]=(ushort)(v.y & 0xffff); d[3]=(ushort)(v.y >> 16);
        d[4]=(ushort)(v.z & 0xffff); d[5]=(ushort)(v.z >> 16);
        d[6]=(ushort)(v.w & 0xffff); d[7]=(ushort)(v.w >> 16);
    }
    __syncthreads();

    const int l = t & 63, dg = t >> 6;
    const int dbase = dg * 16;
    float acc[16] = {};
    for (int mm = 0; mm < 128; ++mm) {
        float q = b2f(qps[l][mm]);
        const float* kr = &kvf[mm][dbase];
        #pragma unroll
        for (int jj = 0; jj < 4; ++jj) {
            float4 v4 = *(const float4*)&kr[jj*4];
            acc[jj*4+0] += q*v4.x; acc[jj*4+1] += q*v4.y;
            acc[jj*4+2] += q*v4.z; acc[jj*4+3] += q*v4.w;
        }
    }
    size_t r = (size_t)(b*L_ + l0 + l) * H_ + h;
    float* o = NUM + r * DH_ + dbase;
    #pragma unroll
    for (int jj = 0; jj < 4; ++jj) {
        *(float4*)&o[jj*4] = make_float4(acc[jj*4+0], acc[jj*4+1], acc[jj*4+2], acc[jj*4+3]);
    }
}

// ---------------------------------------------------------------------------
// att_finish: den = dot(qp, ks); ATT = NUM/den -> bf16
// ---------------------------------------------------------------------------
__global__ __launch_bounds__(256) void att_finish(
    const float* __restrict__ NUM, const ushort* __restrict__ QP,
    const float* __restrict__ KVS, ushort* __restrict__ ATT)
{
    const int t = threadIdx.x;
    const int r = blockIdx.x * 4 + (t >> 6);
    const int lane = t & 63;
    const int b = r >> 16;
    const int h = r & 15;
    const int bh = (b << 4) | h;

    unsigned int u = *(const unsigned int*)(QP + (size_t)r * M_ + 2*lane);
    const float* ksb = KVS + (size_t)bh * M_ * 65 + 64;
    float den = bflo(u) * ksb[(size_t)(2*lane) * 65]
              + bfhi(u) * ksb[(size_t)(2*lane+1) * 65];
    #pragma unroll
    for (int off = 32; off > 0; off >>= 1) den += __shfl_xor(den, off, 64);
    den = fmaxf(den, 1e-10f);   // no-op when correct (den >= ~0.5)

    float nv = NUM[(size_t)r * DH_ + lane];
    ATT[(size_t)r * DH_ + lane] = f2b(nv / den);
}

// ---------------------------------------------------------------------------
extern "C" void kernel_launch(void* const* d_in, const int* in_sizes, int n_in,
                              void* d_out, int out_size, void* d_ws, size_t ws_size,
                              hipStream_t stream)
{
    const float* Xq = (const float*)d_in[0];   // [B,L,HID] f32
    const float* Xs = (const float*)d_in[1];
    const float* Wq = (const float*)d_in[2];   // [HID,H*DH] f32
    const float* Wk = (const float*)d_in[3];
    const float* Wv = (const float*)d_in[4];
    const float* Wo = (const float*)d_in[5];   // [H*DH,HID] f32
    const float* Pj = (const float*)d_in[6];   // [M,DH] f32
    float* out = (float*)d_out;                // [B,L,HID] f32

    char* ws = (char*)d_ws;
    ushort* QPb  = (ushort*)(ws + 0);            // 64MB bf16 [NROW, M]
    ushort* KPb  = (ushort*)(ws + 67108864);     // 64MB bf16
    ushort* Vb   = (ushort*)(ws + 134217728);    // 32MB bf16 (later ATT)
    float*  NUM  = (float*)(ws + 167772160);     // 64MB f32 (KVSP aliases: dead before NUM written)
    float*  KVSP = (float*)(ws + 167772160);     // 17MB f32
    float*  KVS  = (float*)(ws + 234881024);     // 2.1MB f32
    ushort* ATT  = Vb;                           // alias V (dead after kvs_part)

    dim3 tb(256);

    gemm_phi<<<dim3(H_, BL_/64), tb, 0, stream>>>(Xq, Wq, Pj, QPb);
    gemm_phi<<<dim3(H_, BL_/64), tb, 0, stream>>>(Xs, Wk, Pj, KPb);
    gemm_f32_bf16<<<dim3(HID_/64, BL_/64), tb, 0, stream>>>(Xs, Wv, Vb, BL_, HID_, HID_);

    kvs_part_kernel<<<dim3(B_*H_, 8), tb, 0, stream>>>(KPb, Vb, KVSP);
    kvs_reduce_kernel<<<B_*H_, tb, 0, stream>>>(KVSP, KVS);

    num_kernel<<<dim3(B_*H_, L_/64), tb, 0, stream>>>(QPb, KVS, NUM);
    att_finish<<<NROW/4, tb, 0, stream>>>(NUM, QPb, KVS, ATT);

    gemm_bf16_f32<<<dim3(HID_/64, BL_/64), tb, 0, stream>>>(ATT, Wo, out, BL_, HID_, HID_);
    (void)in_sizes; (void)n_in; (void)out_size; (void)ws_size;
}

// Round 7
// 865.800 us; speedup vs baseline: 5.1465x; 3.2372x over previous
//
#include <hip/hip_runtime.h>
#include <hip/hip_bf16.h>

// Performer / FAVOR+ noncausal attention. ALL inputs + output FLOAT32.
// Intermediates bf16/f32. MFMA (16x16x32 bf16) GEMMs, global_load_lds staging.
// R7 fix: workspace offsets (R5/R6 had QP/KP/V/NUM overlaps -> bf16-reads-f32 garbage).
#define B_   4
#define L_   4096
#define HID_ 1024
#define H_   16
#define DH_  64
#define M_   128
#define BL_  (B_*L_)        // 16384
#define NROW (BL_*H_)       // 262144

using short8 = __attribute__((ext_vector_type(8))) short;
using f32x4  = __attribute__((ext_vector_type(4))) float;

__device__ __forceinline__ float b2f(ushort s) {
    return __builtin_bit_cast(float, (unsigned int)s << 16);
}
__device__ __forceinline__ float bflo(unsigned int u) {
    return __builtin_bit_cast(float, u << 16);
}
__device__ __forceinline__ float bfhi(unsigned int u) {
    return __builtin_bit_cast(float, u & 0xffff0000u);
}
__device__ __forceinline__ ushort f2b(float f) {  // RNE
    unsigned int u = __builtin_bit_cast(unsigned int, f);
    u += 0x7fffu + ((u >> 16) & 1u);
    return (ushort)(u >> 16);
}

// async global->LDS, 16B per lane; LDS dest = wave-uniform base + lane*16
__device__ __forceinline__ void gld16(void* lds, const void* g) {
    __builtin_amdgcn_global_load_lds(
        (const __attribute__((address_space(1))) unsigned int*)g,
        (__attribute__((address_space(3))) unsigned int*)lds, 16, 0, 0);
}

// ---------------------------------------------------------------------------
// Core 128x128-tile MFMA K-loop. A[row][k], BT[col][k] bf16, row stride 1024.
// LDS As/Bs layout: [kg(4)][r(128)][8] bf16 (8KB each). 256 thr / 4 waves.
// ---------------------------------------------------------------------------
__device__ __forceinline__ void mfma_gemm_128(
    const ushort* __restrict__ A, const ushort* __restrict__ BT,
    int bm, int bn, ushort* As, ushort* Bs, f32x4 acc[4][4])
{
    const int t = threadIdx.x, w = t >> 6, lane = t & 63;
    const int wm = w >> 1, wn = w & 1, kg = lane >> 4, lr = lane & 15;
    const ushort* a0 = A  + (size_t)(bm + lane)      * HID_ + w * 8;
    const ushort* a1 = A  + (size_t)(bm + 64 + lane) * HID_ + w * 8;
    const ushort* b0 = BT + (size_t)(bn + lane)      * HID_ + w * 8;
    const ushort* b1 = BT + (size_t)(bn + 64 + lane) * HID_ + w * 8;
    ushort* lA0 = As + (size_t)(w * 128) * 8;
    ushort* lA1 = As + (size_t)(w * 128 + 64) * 8;
    ushort* lB0 = Bs + (size_t)(w * 128) * 8;
    ushort* lB1 = Bs + (size_t)(w * 128 + 64) * 8;

    for (int k0 = 0; k0 < HID_; k0 += 32) {
        gld16(lA0, a0 + k0); gld16(lA1, a1 + k0);
        gld16(lB0, b0 + k0); gld16(lB1, b1 + k0);
        __syncthreads();
        short8 av[4], bv[4];
        #pragma unroll
        for (int i = 0; i < 4; ++i)
            av[i] = *(const short8*)(As + ((size_t)kg*128 + wm*64 + i*16 + lr) * 8);
        #pragma unroll
        for (int i = 0; i < 4; ++i)
            bv[i] = *(const short8*)(Bs + ((size_t)kg*128 + wn*64 + i*16 + lr) * 8);
        #pragma unroll
        for (int mt = 0; mt < 4; ++mt)
            #pragma unroll
            for (int nt = 0; nt < 4; ++nt)
                acc[mt][nt] = __builtin_amdgcn_mfma_f32_16x16x32_bf16(
                    av[mt], bv[nt], acc[mt][nt], 0, 0, 0);
        __syncthreads();
    }
}

// ---------------------------------------------------------------------------
// Fused QK projection + phi (all-MFMA).
// grid (HID/128=8, BL/128=128); block covers heads h0=2*bx, h0+1.
// ---------------------------------------------------------------------------
__global__ __launch_bounds__(256) void gemm_phi_mfma(
    const ushort* __restrict__ A, const ushort* __restrict__ BT,
    const float* __restrict__ proj, ushort* __restrict__ OUT)
{
    __shared__ __align__(16) ushort uni[16384];  // main: As=uni, Bs=uni+4096; epi: Aq[2][8][128][8]
    __shared__ __align__(16) ushort pjs[8192];   // proj bf16, B-layout [kg(8)][m(128)][8]
    const int t = threadIdx.x;

    for (int s = t; s < 1024; s += 256) {        // stage proj -> pjs
        int kgs = s >> 7, m = s & 127;
        const float* p = proj + (size_t)m * DH_ + kgs * 8;
        short8 v;
        #pragma unroll
        for (int j = 0; j < 8; ++j) v[j] = (short)f2b(p[j]);
        *(short8*)(pjs + (size_t)s * 8) = v;
    }

    const int bm = blockIdx.y * 128, bn = blockIdx.x * 128, h0 = blockIdx.x * 2;
    f32x4 acc[4][4];
    const f32x4 z4 = {0.f, 0.f, 0.f, 0.f};
    #pragma unroll
    for (int mt = 0; mt < 4; ++mt)
        #pragma unroll
        for (int nt = 0; nt < 4; ++nt) acc[mt][nt] = z4;

    mfma_gemm_128(A, BT, bm, bn, uni, uni + 4096, acc);

    const int w = t >> 6, lane = t & 63, wm = w >> 1, wn = w & 1;
    const int lr = lane & 15, rq = lane >> 4;

    // convert q quadrant -> Aq[head=wn] in A-operand layout [head][kg][row][8]
    #pragma unroll
    for (int mt = 0; mt < 4; ++mt)
        #pragma unroll
        for (int nt = 0; nt < 4; ++nt)
            #pragma unroll
            for (int p = 0; p < 4; ++p) {
                int row = wm * 64 + mt * 16 + rq * 4 + p;
                int d   = nt * 16 + lr;
                uni[(((size_t)wn * 8 + (d >> 3)) * 128 + row) * 8 + (d & 7)]
                    = f2b(acc[mt][nt][p]);
            }
    __syncthreads();

    const float ratio = 0.08838834764831845f;
    for (int hs = 0; hs < 2; ++hs) {
        f32x4 a2[4][4];
        #pragma unroll
        for (int mt = 0; mt < 4; ++mt)
            #pragma unroll
            for (int nt = 0; nt < 4; ++nt) a2[mt][nt] = z4;
        #pragma unroll
        for (int ks = 0; ks < 2; ++ks) {
            short8 av[4], bv[4];
            #pragma unroll
            for (int i = 0; i < 4; ++i)
                av[i] = *(const short8*)(uni +
                    (((size_t)hs*8 + ks*4 + rq) * 128 + wm*64 + i*16 + lr) * 8);
            #pragma unroll
            for (int i = 0; i < 4; ++i)
                bv[i] = *(const short8*)(pjs +
                    (((size_t)ks*4 + rq) * 128 + wn*64 + i*16 + lr) * 8);
            #pragma unroll
            for (int mt = 0; mt < 4; ++mt)
                #pragma unroll
                for (int nt = 0; nt < 4; ++nt)
                    a2[mt][nt] = __builtin_amdgcn_mfma_f32_16x16x32_bf16(
                        av[mt], bv[nt], a2[mt][nt], 0, 0, 0);
        }
        #pragma unroll
        for (int mt = 0; mt < 4; ++mt)
            #pragma unroll
            for (int nt = 0; nt < 4; ++nt)
                #pragma unroll
                for (int p = 0; p < 4; ++p) {
                    size_t rowg = bm + wm*64 + mt*16 + rq*4 + p;
                    int m = wn*64 + nt*16 + lr;
                    float v = fmaxf(a2[mt][nt][p] * ratio, 0.f) + 1e-3f;
                    OUT[(rowg * H_ + (h0 + hs)) * M_ + m] = f2b(v);
                }
    }
}

// ---------------------------------------------------------------------------
// Plain MFMA GEMM, bf16 out (V projection)
// ---------------------------------------------------------------------------
__global__ __launch_bounds__(256) void gemm_mfma_bf16(
    const ushort* __restrict__ A, const ushort* __restrict__ BT,
    ushort* __restrict__ C)
{
    __shared__ __align__(16) ushort As[4096], Bs[4096];
    const int bm = blockIdx.y * 128, bn = blockIdx.x * 128;
    f32x4 acc[4][4];
    const f32x4 z4 = {0.f, 0.f, 0.f, 0.f};
    #pragma unroll
    for (int mt = 0; mt < 4; ++mt)
        #pragma unroll
        for (int nt = 0; nt < 4; ++nt) acc[mt][nt] = z4;
    mfma_gemm_128(A, BT, bm, bn, As, Bs, acc);
    const int t = threadIdx.x, w = t >> 6, lane = t & 63;
    const int wm = w >> 1, wn = w & 1, lr = lane & 15, rq = lane >> 4;
    #pragma unroll
    for (int mt = 0; mt < 4; ++mt)
        #pragma unroll
        for (int nt = 0; nt < 4; ++nt)
            #pragma unroll
            for (int p = 0; p < 4; ++p) {
                size_t row = bm + wm*64 + mt*16 + rq*4 + p;
                int col = bn + wn*64 + nt*16 + lr;
                C[row * HID_ + col] = f2b(acc[mt][nt][p]);
            }
}

// ---------------------------------------------------------------------------
// Plain MFMA GEMM, f32 out (output projection)
// ---------------------------------------------------------------------------
__global__ __launch_bounds__(256) void gemm_mfma_f32(
    const ushort* __restrict__ A, const ushort* __restrict__ BT,
    float* __restrict__ C)
{
    __shared__ __align__(16) ushort As[4096], Bs[4096];
    const int bm = blockIdx.y * 128, bn = blockIdx.x * 128;
    f32x4 acc[4][4];
    const f32x4 z4 = {0.f, 0.f, 0.f, 0.f};
    #pragma unroll
    for (int mt = 0; mt < 4; ++mt)
        #pragma unroll
        for (int nt = 0; nt < 4; ++nt) acc[mt][nt] = z4;
    mfma_gemm_128(A, BT, bm, bn, As, Bs, acc);
    const int t = threadIdx.x, w = t >> 6, lane = t & 63;
    const int wm = w >> 1, wn = w & 1, lr = lane & 15, rq = lane >> 4;
    #pragma unroll
    for (int mt = 0; mt < 4; ++mt)
        #pragma unroll
        for (int nt = 0; nt < 4; ++nt)
            #pragma unroll
            for (int p = 0; p < 4; ++p) {
                size_t row = bm + wm*64 + mt*16 + rq*4 + p;
                int col = bn + wn*64 + nt*16 + lr;
                C[row * HID_ + col] = acc[mt][nt][p];
            }
}

// ---------------------------------------------------------------------------
// f32 -> bf16 elementwise convert (X inputs)
// ---------------------------------------------------------------------------
__global__ __launch_bounds__(256) void cvt_bf16(
    const float* __restrict__ X, ushort* __restrict__ Y, int n4)
{
    for (int i = blockIdx.x * 256 + threadIdx.x; i < n4; i += gridDim.x * 256) {
        float4 v = ((const float4*)X)[i];
        ushort4 o;
        o.x = f2b(v.x); o.y = f2b(v.y); o.z = f2b(v.z); o.w = f2b(v.w);
        ((ushort4*)Y)[i] = o;
    }
}

// ---------------------------------------------------------------------------
// W[k][n] f32 -> WT[n][k] bf16 (1024x1024), 64x64 tiles
// ---------------------------------------------------------------------------
__global__ __launch_bounds__(256) void wtrans(
    const float* __restrict__ W, ushort* __restrict__ WT)
{
    __shared__ float tile[64][65];
    const int k0 = blockIdx.y * 64, n0 = blockIdx.x * 64;
    const int t = threadIdx.x;
    for (int i = t; i < 1024; i += 256) {
        int r = i >> 4, c4 = i & 15;
        float4 v = *(const float4*)(W + (size_t)(k0 + r) * HID_ + n0 + c4 * 4);
        tile[r][c4*4+0] = v.x; tile[r][c4*4+1] = v.y;
        tile[r][c4*4+2] = v.z; tile[r][c4*4+3] = v.w;
    }
    __syncthreads();
    for (int i = t; i < 1024; i += 256) {
        int n = i >> 4, c4 = i & 15;
        ushort4 o;
        o.x = f2b(tile[c4*4+0][n]); o.y = f2b(tile[c4*4+1][n]);
        o.z = f2b(tile[c4*4+2][n]); o.w = f2b(tile[c4*4+3][n]);
        *(ushort4*)(WT + (size_t)(n0 + n) * HID_ + k0 + c4 * 4) = o;
    }
}

// ---------------------------------------------------------------------------
// kvs_part / kvs_reduce / num / att_finish (unchanged, pass-verified round 4)
// ---------------------------------------------------------------------------
__global__ __launch_bounds__(256) void kvs_part_kernel(
    const ushort* __restrict__ KP, const ushort* __restrict__ V,
    float* __restrict__ KVSP)
{
    __shared__ ushort kps[128][128];
    __shared__ ushort vsh[128][64];
    const int bh = blockIdx.x;
    const int b = bh >> 4, h = bh & 15;
    const int t = threadIdx.x;
    const int m = t & 127, dg = t >> 7;
    float acc[32] = {};
    float accs = 0.f;

    for (int sub = 0; sub < 4; ++sub) {
        const int lbase = blockIdx.y * 512 + sub * 128;
        for (int i = t; i < 128*16; i += 256) {
            int l = i >> 4, pos = i & 15;
            size_t g = ((size_t)(b*L_ + lbase + l) * H_ + h) * M_ + pos*8;
            *(uint4*)&kps[l][pos*8] = *(const uint4*)&KP[g];
        }
        for (int i = t; i < 128*8; i += 256) {
            int l = i >> 3, pos = i & 7;
            size_t g = ((size_t)(b*L_ + lbase + l) * H_ + h) * DH_ + pos*8;
            *(uint4*)&vsh[l][pos*8] = *(const uint4*)&V[g];
        }
        __syncthreads();
        for (int l = 0; l < 128; ++l) {
            float kp = b2f(kps[l][m]);
            if (dg == 0) accs += kp;
            const unsigned int* vr = (const unsigned int*)&vsh[l][dg*32];
            #pragma unroll
            for (int j = 0; j < 16; ++j) {
                unsigned int u = vr[j];
                acc[2*j]   += kp * bflo(u);
                acc[2*j+1] += kp * bfhi(u);
            }
        }
        __syncthreads();
    }
    float* dst = KVSP + ((size_t)(blockIdx.y * 64 + bh) * M_ + m) * 65;
    #pragma unroll
    for (int j = 0; j < 32; ++j) dst[dg*32 + j] = acc[j];
    if (dg == 0) dst[64] = accs;
}

__global__ __launch_bounds__(256) void kvs_reduce_kernel(
    const float* __restrict__ KVSP, float* __restrict__ KVS)
{
    const int bh = blockIdx.x;
    for (int i = threadIdx.x; i < M_*65; i += 256) {
        float s = 0.f;
        #pragma unroll
        for (int p = 0; p < 8; ++p)
            s += KVSP[(size_t)(p*64 + bh) * (M_*65) + i];
        KVS[(size_t)bh * (M_*65) + i] = s;
    }
}

__global__ __launch_bounds__(256) void num_kernel(
    const ushort* __restrict__ QP, const float* __restrict__ KVS,
    float* __restrict__ NUM)
{
    __shared__ ushort qps[64][130];
    __shared__ float  kvf[128][64];
    const int bh = blockIdx.x;
    const int b = bh >> 4, h = bh & 15;
    const int l0 = blockIdx.y * 64;
    const int t = threadIdx.x;

    for (int i = t; i < 128*64; i += 256) {
        int mm = i >> 6, c = i & 63;
        kvf[mm][c] = KVS[((size_t)bh * M_ + mm) * 65 + c];
    }
    for (int i = t; i < 64*16; i += 256) {
        int l = i >> 4, pos = i & 15;
        size_t g = ((size_t)(b*L_ + l0 + l) * H_ + h) * M_ + pos*8;
        uint4 v = *(const uint4*)&QP[g];
        ushort* d = &qps[l][pos*8];
        d[0]=(ushort)(v.x & 0xffff); d[1]=(ushort)(v.x >> 16);
        d[2]=(ushort)(v.y & 0xffff); d[3]=(ushort)(v.y >> 16);
        d[4]=(ushort)(v.z & 0xffff); d[5]=(ushort)(v.z >> 16);
        d[6]=(ushort)(v.w & 0xffff); d[7]=(ushort)(v.w >> 16);
    }
    __syncthreads();

    const int l = t & 63, dg = t >> 6;
    const int dbase = dg * 16;
    float acc[16] = {};
    for (int mm = 0; mm < 128; ++mm) {
        float q = b2f(qps[l][mm]);
        const float* kr = &kvf[mm][dbase];
        #pragma unroll
        for (int jj = 0; jj < 4; ++jj) {
            float4 v4 = *(const float4*)&kr[jj*4];
            acc[jj*4+0] += q*v4.x; acc[jj*4+1] += q*v4.y;
            acc[jj*4+2] += q*v4.z; acc[jj*4+3] += q*v4.w;
        }
    }
    size_t r = (size_t)(b*L_ + l0 + l) * H_ + h;
    float* o = NUM + r * DH_ + dbase;
    #pragma unroll
    for (int jj = 0; jj < 4; ++jj) {
        *(float4*)&o[jj*4] = make_float4(acc[jj*4+0], acc[jj*4+1], acc[jj*4+2], acc[jj*4+3]);
    }
}

__global__ __launch_bounds__(256) void att_finish(
    const float* __restrict__ NUM, const ushort* __restrict__ QP,
    const float* __restrict__ KVS, ushort* __restrict__ ATT)
{
    const int t = threadIdx.x;
    const int r = blockIdx.x * 4 + (t >> 6);
    const int lane = t & 63;
    const int b = r >> 16;
    const int h = r & 15;
    const int bh = (b << 4) | h;

    unsigned int u = *(const unsigned int*)(QP + (size_t)r * M_ + 2*lane);
    const float* ksb = KVS + (size_t)bh * M_ * 65 + 64;
    float den = bflo(u) * ksb[(size_t)(2*lane) * 65]
              + bfhi(u) * ksb[(size_t)(2*lane+1) * 65];
    #pragma unroll
    for (int off = 32; off > 0; off >>= 1) den += __shfl_xor(den, off, 64);
    den = fmaxf(den, 1e-10f);

    float nv = NUM[(size_t)r * DH_ + lane];
    ATT[(size_t)r * DH_ + lane] = f2b(nv / den);
}

// ---------------------------------------------------------------------------
extern "C" void kernel_launch(void* const* d_in, const int* in_sizes, int n_in,
                              void* d_out, int out_size, void* d_ws, size_t ws_size,
                              hipStream_t stream)
{
    const float* Xq = (const float*)d_in[0];
    const float* Xs = (const float*)d_in[1];
    const float* Wq = (const float*)d_in[2];
    const float* Wk = (const float*)d_in[3];
    const float* Wv = (const float*)d_in[4];
    const float* Wo = (const float*)d_in[5];
    const float* Pj = (const float*)d_in[6];
    float* out = (float*)d_out;

    // Fixed layout (all MB-aligned, audited disjoint per stage):
    char* ws = (char*)d_ws;
    ushort* WqT = (ushort*)(ws + 0);            // [0,2)MB
    ushort* WkT = (ushort*)(ws + 2097152);      // [2,4)
    ushort* WvT = (ushort*)(ws + 4194304);      // [4,6)
    ushort* WoT = (ushort*)(ws + 6291456);      // [6,8)
    ushort* Xqb = (ushort*)(ws + 8388608);      // [8,40)   dead after Q-gemm
    ushort* Xsb = (ushort*)(ws + 41943040);     // [40,72)
    ushort* QPb = (ushort*)(ws + 75497472);     // [72,136)
    ushort* KPb = (ushort*)(ws + 142606336);    // [136,200) dead after kvs_part
    ushort* Vb  = (ushort*)(ws + 209715200);    // [200,232) dead after kvs_part
    float*  KVSP = (float*)(ws + 8388608);      // [8,~25.4) alias Xqb
    float*  KVS  = (float*)(ws + 25427968);     // [~25.4,~27.5)
    float*  NUM  = (float*)(ws + 142606336);    // alias KPb
    ushort* ATT  = Vb;                          // alias Vb

    dim3 tb(256);

    cvt_bf16<<<4096, tb, 0, stream>>>(Xq, Xqb, BL_*HID_/4);
    cvt_bf16<<<4096, tb, 0, stream>>>(Xs, Xsb, BL_*HID_/4);
    wtrans<<<dim3(16,16), tb, 0, stream>>>(Wq, WqT);
    wtrans<<<dim3(16,16), tb, 0, stream>>>(Wk, WkT);
    wtrans<<<dim3(16,16), tb, 0, stream>>>(Wv, WvT);
    wtrans<<<dim3(16,16), tb, 0, stream>>>(Wo, WoT);

    gemm_phi_mfma<<<dim3(8, 128), tb, 0, stream>>>(Xqb, WqT, Pj, QPb);
    gemm_phi_mfma<<<dim3(8, 128), tb, 0, stream>>>(Xsb, WkT, Pj, KPb);
    gemm_mfma_bf16<<<dim3(8, 128), tb, 0, stream>>>(Xsb, WvT, Vb);

    kvs_part_kernel<<<dim3(B_*H_, 8), tb, 0, stream>>>(KPb, Vb, KVSP);
    kvs_reduce_kernel<<<B_*H_, tb, 0, stream>>>(KVSP, KVS);

    num_kernel<<<dim3(B_*H_, L_/64), tb, 0, stream>>>(QPb, KVS, NUM);
    att_finish<<<NROW/4, tb, 0, stream>>>(NUM, QPb, KVS, ATT);

    gemm_mfma_f32<<<dim3(8, 128), tb, 0, stream>>>(ATT, WoT, out);
    (void)in_sizes; (void)n_in; (void)out_size; (void)ws_size;
}

// Round 8
// 748.391 us; speedup vs baseline: 5.9539x; 1.1569x over previous
//
#include <hip/hip_runtime.h>
#include <hip/hip_bf16.h>

// Performer / FAVOR+ noncausal attention. ALL inputs + output FLOAT32.
// Intermediates bf16/f32. MFMA (16x16x32 bf16) for GEMMs + fused num/den.
#define B_   4
#define L_   4096
#define HID_ 1024
#define H_   16
#define DH_  64
#define M_   128
#define BL_  (B_*L_)        // 16384
#define NROW (BL_*H_)       // 262144

using short8 = __attribute__((ext_vector_type(8))) short;
using f32x4  = __attribute__((ext_vector_type(4))) float;

__device__ __forceinline__ float b2f(ushort s) {
    return __builtin_bit_cast(float, (unsigned int)s << 16);
}
__device__ __forceinline__ float bflo(unsigned int u) {
    return __builtin_bit_cast(float, u << 16);
}
__device__ __forceinline__ float bfhi(unsigned int u) {
    return __builtin_bit_cast(float, u & 0xffff0000u);
}
__device__ __forceinline__ ushort f2b(float f) {  // RNE
    unsigned int u = __builtin_bit_cast(unsigned int, f);
    u += 0x7fffu + ((u >> 16) & 1u);
    return (ushort)(u >> 16);
}

// async global->LDS, 16B per lane; LDS dest = wave-uniform base + lane*16
__device__ __forceinline__ void gld16(void* lds, const void* g) {
    __builtin_amdgcn_global_load_lds(
        (const __attribute__((address_space(1))) unsigned int*)g,
        (__attribute__((address_space(3))) unsigned int*)lds, 16, 0, 0);
}

// ---------------------------------------------------------------------------
// Generalized 128x128-tile MFMA K-loop. A[row][k] stride sA, BT[col][k] stride
// sB (both k-contiguous, 16B-aligned). LDS As/Bs: [kg(4)][r(128)][8] (8KB ea).
// 256 thr / 4 waves; wave w: rows (w>>1)*64.., cols (w&1)*64..; acc[4][4].
// ---------------------------------------------------------------------------
__device__ __forceinline__ void mfma_gemm_g(
    const ushort* __restrict__ A, const ushort* __restrict__ BT,
    int sA, int sB, int K, ushort* As, ushort* Bs, f32x4 acc[4][4])
{
    const int t = threadIdx.x, w = t >> 6, lane = t & 63;
    const int wm = w >> 1, wn = w & 1, kg = lane >> 4, lr = lane & 15;
    const ushort* a0 = A  + (size_t)lane * sA + w * 8;
    const ushort* a1 = A  + (size_t)(64 + lane) * sA + w * 8;
    const ushort* b0 = BT + (size_t)lane * sB + w * 8;
    const ushort* b1 = BT + (size_t)(64 + lane) * sB + w * 8;
    ushort* lA0 = As + (size_t)(w * 128) * 8;
    ushort* lA1 = As + (size_t)(w * 128 + 64) * 8;
    ushort* lB0 = Bs + (size_t)(w * 128) * 8;
    ushort* lB1 = Bs + (size_t)(w * 128 + 64) * 8;

    for (int k0 = 0; k0 < K; k0 += 32) {
        gld16(lA0, a0 + k0); gld16(lA1, a1 + k0);
        gld16(lB0, b0 + k0); gld16(lB1, b1 + k0);
        __syncthreads();
        short8 av[4], bv[4];
        #pragma unroll
        for (int i = 0; i < 4; ++i)
            av[i] = *(const short8*)(As + ((size_t)kg*128 + wm*64 + i*16 + lr) * 8);
        #pragma unroll
        for (int i = 0; i < 4; ++i)
            bv[i] = *(const short8*)(Bs + ((size_t)kg*128 + wn*64 + i*16 + lr) * 8);
        #pragma unroll
        for (int mt = 0; mt < 4; ++mt)
            #pragma unroll
            for (int nt = 0; nt < 4; ++nt)
                acc[mt][nt] = __builtin_amdgcn_mfma_f32_16x16x32_bf16(
                    av[mt], bv[nt], acc[mt][nt], 0, 0, 0);
        __syncthreads();
    }
}

// ---------------------------------------------------------------------------
// Fused QK projection + phi (all-MFMA).
// grid (HID/128=8, BL/128=128); block covers heads h0=2*bx, h0+1.
// ---------------------------------------------------------------------------
__global__ __launch_bounds__(256) void gemm_phi_mfma(
    const ushort* __restrict__ A, const ushort* __restrict__ BT,
    const float* __restrict__ proj, ushort* __restrict__ OUT)
{
    __shared__ __align__(16) ushort uni[16384];  // main: As/Bs; epi: Aq[2][8][128][8]
    __shared__ __align__(16) ushort pjs[8192];   // proj bf16, B-layout [kg(8)][m(128)][8]
    const int t = threadIdx.x;

    for (int s = t; s < 1024; s += 256) {        // stage proj -> pjs
        int kgs = s >> 7, m = s & 127;
        const float* p = proj + (size_t)m * DH_ + kgs * 8;
        short8 v;
        #pragma unroll
        for (int j = 0; j < 8; ++j) v[j] = (short)f2b(p[j]);
        *(short8*)(pjs + (size_t)s * 8) = v;
    }

    const int bm = blockIdx.y * 128, bn = blockIdx.x * 128, h0 = blockIdx.x * 2;
    f32x4 acc[4][4];
    const f32x4 z4 = {0.f, 0.f, 0.f, 0.f};
    #pragma unroll
    for (int mt = 0; mt < 4; ++mt)
        #pragma unroll
        for (int nt = 0; nt < 4; ++nt) acc[mt][nt] = z4;

    mfma_gemm_g(A + (size_t)bm * HID_, BT + (size_t)bn * HID_,
                HID_, HID_, HID_, uni, uni + 4096, acc);

    const int w = t >> 6, lane = t & 63, wm = w >> 1, wn = w & 1;
    const int lr = lane & 15, rq = lane >> 4;

    // convert q quadrant -> Aq[head=wn] in A-operand layout [head][kg][row][8]
    #pragma unroll
    for (int mt = 0; mt < 4; ++mt)
        #pragma unroll
        for (int nt = 0; nt < 4; ++nt)
            #pragma unroll
            for (int p = 0; p < 4; ++p) {
                int row = wm * 64 + mt * 16 + rq * 4 + p;
                int d   = nt * 16 + lr;
                uni[(((size_t)wn * 8 + (d >> 3)) * 128 + row) * 8 + (d & 7)]
                    = f2b(acc[mt][nt][p]);
            }
    __syncthreads();

    const float ratio = 0.08838834764831845f;
    for (int hs = 0; hs < 2; ++hs) {
        f32x4 a2[4][4];
        #pragma unroll
        for (int mt = 0; mt < 4; ++mt)
            #pragma unroll
            for (int nt = 0; nt < 4; ++nt) a2[mt][nt] = z4;
        #pragma unroll
        for (int ks = 0; ks < 2; ++ks) {
            short8 av[4], bv[4];
            #pragma unroll
            for (int i = 0; i < 4; ++i)
                av[i] = *(const short8*)(uni +
                    (((size_t)hs*8 + ks*4 + rq) * 128 + wm*64 + i*16 + lr) * 8);
            #pragma unroll
            for (int i = 0; i < 4; ++i)
                bv[i] = *(const short8*)(pjs +
                    (((size_t)ks*4 + rq) * 128 + wn*64 + i*16 + lr) * 8);
            #pragma unroll
            for (int mt = 0; mt < 4; ++mt)
                #pragma unroll
                for (int nt = 0; nt < 4; ++nt)
                    a2[mt][nt] = __builtin_amdgcn_mfma_f32_16x16x32_bf16(
                        av[mt], bv[nt], a2[mt][nt], 0, 0, 0);
        }
        #pragma unroll
        for (int mt = 0; mt < 4; ++mt)
            #pragma unroll
            for (int nt = 0; nt < 4; ++nt)
                #pragma unroll
                for (int p = 0; p < 4; ++p) {
                    size_t rowg = bm + wm*64 + mt*16 + rq*4 + p;
                    int m = wn*64 + nt*16 + lr;
                    float v = fmaxf(a2[mt][nt][p] * ratio, 0.f) + 1e-3f;
                    OUT[(rowg * H_ + (h0 + hs)) * M_ + m] = f2b(v);
                }
    }
}

// ---------------------------------------------------------------------------
// Plain MFMA GEMM, bf16 out (V projection)
// ---------------------------------------------------------------------------
__global__ __launch_bounds__(256) void gemm_mfma_bf16(
    const ushort* __restrict__ A, const ushort* __restrict__ BT,
    ushort* __restrict__ C)
{
    __shared__ __align__(16) ushort As[4096], Bs[4096];
    const int bm = blockIdx.y * 128, bn = blockIdx.x * 128;
    f32x4 acc[4][4];
    const f32x4 z4 = {0.f, 0.f, 0.f, 0.f};
    #pragma unroll
    for (int mt = 0; mt < 4; ++mt)
        #pragma unroll
        for (int nt = 0; nt < 4; ++nt) acc[mt][nt] = z4;
    mfma_gemm_g(A + (size_t)bm * HID_, BT + (size_t)bn * HID_,
                HID_, HID_, HID_, As, Bs, acc);
    const int t = threadIdx.x, w = t >> 6, lane = t & 63;
    const int wm = w >> 1, wn = w & 1, lr = lane & 15, rq = lane >> 4;
    #pragma unroll
    for (int mt = 0; mt < 4; ++mt)
        #pragma unroll
        for (int nt = 0; nt < 4; ++nt)
            #pragma unroll
            for (int p = 0; p < 4; ++p) {
                size_t row = bm + wm*64 + mt*16 + rq*4 + p;
                int col = bn + wn*64 + nt*16 + lr;
                C[row * HID_ + col] = f2b(acc[mt][nt][p]);
            }
}

// ---------------------------------------------------------------------------
// Plain MFMA GEMM, f32 out (output projection)
// ---------------------------------------------------------------------------
__global__ __launch_bounds__(256) void gemm_mfma_f32(
    const ushort* __restrict__ A, const ushort* __restrict__ BT,
    float* __restrict__ C)
{
    __shared__ __align__(16) ushort As[4096], Bs[4096];
    const int bm = blockIdx.y * 128, bn = blockIdx.x * 128;
    f32x4 acc[4][4];
    const f32x4 z4 = {0.f, 0.f, 0.f, 0.f};
    #pragma unroll
    for (int mt = 0; mt < 4; ++mt)
        #pragma unroll
        for (int nt = 0; nt < 4; ++nt) acc[mt][nt] = z4;
    mfma_gemm_g(A + (size_t)bm * HID_, BT + (size_t)bn * HID_,
                HID_, HID_, HID_, As, Bs, acc);
    const int t = threadIdx.x, w = t >> 6, lane = t & 63;
    const int wm = w >> 1, wn = w & 1, lr = lane & 15, rq = lane >> 4;
    #pragma unroll
    for (int mt = 0; mt < 4; ++mt)
        #pragma unroll
        for (int nt = 0; nt < 4; ++nt)
            #pragma unroll
            for (int p = 0; p < 4; ++p) {
                size_t row = bm + wm*64 + mt*16 + rq*4 + p;
                int col = bn + wn*64 + nt*16 + lr;
                C[row * HID_ + col] = acc[mt][nt][p];
            }
}

// ---------------------------------------------------------------------------
// f32 -> bf16 elementwise convert (X inputs)
// ---------------------------------------------------------------------------
__global__ __launch_bounds__(256) void cvt_bf16(
    const float* __restrict__ X, ushort* __restrict__ Y, int n4)
{
    for (int i = blockIdx.x * 256 + threadIdx.x; i < n4; i += gridDim.x * 256) {
        float4 v = ((const float4*)X)[i];
        ushort4 o;
        o.x = f2b(v.x); o.y = f2b(v.y); o.z = f2b(v.z); o.w = f2b(v.w);
        ((ushort4*)Y)[i] = o;
    }
}

// ---------------------------------------------------------------------------
// W[k][n] f32 -> WT[n][k] bf16 (1024x1024), 64x64 tiles
// ---------------------------------------------------------------------------
__global__ __launch_bounds__(256) void wtrans(
    const float* __restrict__ W, ushort* __restrict__ WT)
{
    __shared__ float tile[64][65];
    const int k0 = blockIdx.y * 64, n0 = blockIdx.x * 64;
    const int t = threadIdx.x;
    for (int i = t; i < 1024; i += 256) {
        int r = i >> 4, c4 = i & 15;
        float4 v = *(const float4*)(W + (size_t)(k0 + r) * HID_ + n0 + c4 * 4);
        tile[r][c4*4+0] = v.x; tile[r][c4*4+1] = v.y;
        tile[r][c4*4+2] = v.z; tile[r][c4*4+3] = v.w;
    }
    __syncthreads();
    for (int i = t; i < 1024; i += 256) {
        int n = i >> 4, c4 = i & 15;
        ushort4 o;
        o.x = f2b(tile[c4*4+0][n]); o.y = f2b(tile[c4*4+1][n]);
        o.z = f2b(tile[c4*4+2][n]); o.w = f2b(tile[c4*4+3][n]);
        *(ushort4*)(WT + (size_t)(n0 + n) * HID_ + k0 + c4 * 4) = o;
    }
}

// ---------------------------------------------------------------------------
// kvs_part: partial KVS over a 512-l chunk; V converted to f32 at staging
// (unpack once per element instead of once per (element,m) in the loop).
// 64-l subtiles: kps 16KB + vs 16KB = 32KB LDS.
// KVSP[part][bh][m][65]: [0..63]=sum kp*v; [64]=sum kp
// ---------------------------------------------------------------------------
__global__ __launch_bounds__(256) void kvs_part_kernel(
    const ushort* __restrict__ KP, const ushort* __restrict__ V,
    float* __restrict__ KVSP)
{
    __shared__ ushort kps[64][128];    // [l][m] bf16, 16KB
    __shared__ float  vs[64][64];      // [l][d] f32,  16KB
    const int bh = blockIdx.x;
    const int b = bh >> 4, h = bh & 15;
    const int t = threadIdx.x;
    const int m = t & 127, dg = t >> 7;   // dg uniform per wave
    float acc[32] = {};
    float accs = 0.f;

    for (int sub = 0; sub < 8; ++sub) {
        const int lbase = blockIdx.y * 512 + sub * 64;
        for (int i = t; i < 64*16; i += 256) {           // KP tile, uint4 units
            int l = i >> 4, pos = i & 15;
            size_t g = ((size_t)(b*L_ + lbase + l) * H_ + h) * M_ + pos*8;
            *(uint4*)&kps[l][pos*8] = *(const uint4*)&KP[g];
        }
        for (int i = t; i < 64*8; i += 256) {            // V tile bf16->f32
            int l = i >> 3, pos = i & 7;
            size_t g = ((size_t)(b*L_ + lbase + l) * H_ + h) * DH_ + pos*8;
            uint4 v = *(const uint4*)&V[g];
            float* d = &vs[l][pos*8];
            d[0]=bflo(v.x); d[1]=bfhi(v.x); d[2]=bflo(v.y); d[3]=bfhi(v.y);
            d[4]=bflo(v.z); d[5]=bfhi(v.z); d[6]=bflo(v.w); d[7]=bfhi(v.w);
        }
        __syncthreads();
        for (int l = 0; l < 64; ++l) {
            float kp = b2f(kps[l][m]);
            if (dg == 0) accs += kp;
            const float* vr = &vs[l][dg*32];
            #pragma unroll
            for (int j = 0; j < 8; ++j) {
                float4 v4 = *(const float4*)&vr[j*4];    // broadcast read
                acc[j*4+0] += kp*v4.x; acc[j*4+1] += kp*v4.y;
                acc[j*4+2] += kp*v4.z; acc[j*4+3] += kp*v4.w;
            }
        }
        __syncthreads();
    }
    float* dst = KVSP + ((size_t)(blockIdx.y * 64 + bh) * M_ + m) * 65;
    #pragma unroll
    for (int j = 0; j < 32; ++j) dst[dg*32 + j] = acc[j];
    if (dg == 0) dst[64] = accs;
}

// ---------------------------------------------------------------------------
// kvs_reduce: sum 8 partials, transpose, bf16:
// KVSt[bh][d][m] (d<64) = kvs; [64][m] = ks_sum; [65..127][m] = 0
// ---------------------------------------------------------------------------
__global__ __launch_bounds__(256) void kvs_reduce_kernel(
    const float* __restrict__ KVSP, ushort* __restrict__ KVSt)
{
    const int bh = blockIdx.x;
    for (int i = threadIdx.x; i < 128*128; i += 256) {
        int d = i >> 7, m = i & 127;
        ushort v = 0;
        if (d <= 64) {
            float s = 0.f;
            #pragma unroll
            for (int p = 0; p < 8; ++p)
                s += KVSP[((size_t)(p*64 + bh) * M_ + m) * 65 + d];
            v = f2b(s);
        }
        KVSt[(size_t)bh * 16384 + i] = v;
    }
}

// ---------------------------------------------------------------------------
// numden: per (b,h), 128-row tile: [QP rows, K=128 m] x KVSt[128][128].
// Output cols 0..63 = num, col 64 = den -> ATT = num/den (bf16) directly.
// grid (bh=64, L/128=32).
// ---------------------------------------------------------------------------
__global__ __launch_bounds__(256) void numden_mfma(
    const ushort* __restrict__ QP, const ushort* __restrict__ KVSt,
    ushort* __restrict__ ATT)
{
    __shared__ __align__(16) ushort As[4096], Bs[4096];
    __shared__ float sden[128];
    const int bh = blockIdx.x, b = bh >> 4, h = bh & 15;
    const int l0 = blockIdx.y * 128;
    const ushort* Abase = QP + ((size_t)(b * L_ + l0) * H_ + h) * M_;
    const ushort* Bbase = KVSt + (size_t)bh * 16384;

    f32x4 acc[4][4];
    const f32x4 z4 = {0.f, 0.f, 0.f, 0.f};
    #pragma unroll
    for (int mt = 0; mt < 4; ++mt)
        #pragma unroll
        for (int nt = 0; nt < 4; ++nt) acc[mt][nt] = z4;

    mfma_gemm_g(Abase, Bbase, H_*M_, 128, 128, As, Bs, acc);

    const int t = threadIdx.x, w = t >> 6, lane = t & 63;
    const int wm = w >> 1, wn = w & 1, lr = lane & 15, rq = lane >> 4;

    if (wn == 1 && lr == 0) {       // col 64 = den
        #pragma unroll
        for (int mt = 0; mt < 4; ++mt)
            #pragma unroll
            for (int p = 0; p < 4; ++p)
                sden[wm*64 + mt*16 + rq*4 + p] = acc[mt][0][p];
    }
    __syncthreads();

    if (wn == 0) {
        #pragma unroll
        for (int mt = 0; mt < 4; ++mt) {
            #pragma unroll
            for (int p = 0; p < 4; ++p) {
                int row = wm*64 + mt*16 + rq*4 + p;
                float den = fmaxf(sden[row], 1e-10f);
                float rden = 1.0f / den;
                size_t gbase = (size_t)(b * L_ + l0 + row) * HID_ + h * DH_;
                #pragma unroll
                for (int nt = 0; nt < 4; ++nt)
                    ATT[gbase + nt*16 + lr] = f2b(acc[mt][nt][p] * rden);
            }
        }
    }
}

// ---------------------------------------------------------------------------
extern "C" void kernel_launch(void* const* d_in, const int* in_sizes, int n_in,
                              void* d_out, int out_size, void* d_ws, size_t ws_size,
                              hipStream_t stream)
{
    const float* Xq = (const float*)d_in[0];
    const float* Xs = (const float*)d_in[1];
    const float* Wq = (const float*)d_in[2];
    const float* Wk = (const float*)d_in[3];
    const float* Wv = (const float*)d_in[4];
    const float* Wo = (const float*)d_in[5];
    const float* Pj = (const float*)d_in[6];
    float* out = (float*)d_out;

    // Workspace layout (MB-aligned, audited disjoint per stage):
    char* ws = (char*)d_ws;
    ushort* WqT = (ushort*)(ws + 0);            // [0,2)MB
    ushort* WkT = (ushort*)(ws + 2097152);      // [2,4)
    ushort* WvT = (ushort*)(ws + 4194304);      // [4,6)
    ushort* WoT = (ushort*)(ws + 6291456);      // [6,8)
    ushort* Xqb = (ushort*)(ws + 8388608);      // [8,40)   dead after Q-gemm
    ushort* Xsb = (ushort*)(ws + 41943040);     // [40,72)
    ushort* QPb = (ushort*)(ws + 75497472);     // [72,136)
    ushort* KPb = (ushort*)(ws + 142606336);    // [136,200) dead after kvs_part
    ushort* Vb  = (ushort*)(ws + 209715200);    // [200,232) dead after kvs_part
    float*  KVSP = (float*)(ws + 8388608);      // [8,~25.4) alias Xqb
    ushort* KVSt = (ushort*)(ws + 25427968);    // 2MB bf16 [bh][128][128]
    ushort* ATT  = Vb;                          // alias Vb

    dim3 tb(256);

    cvt_bf16<<<4096, tb, 0, stream>>>(Xq, Xqb, BL_*HID_/4);
    cvt_bf16<<<4096, tb, 0, stream>>>(Xs, Xsb, BL_*HID_/4);
    wtrans<<<dim3(16,16), tb, 0, stream>>>(Wq, WqT);
    wtrans<<<dim3(16,16), tb, 0, stream>>>(Wk, WkT);
    wtrans<<<dim3(16,16), tb, 0, stream>>>(Wv, WvT);
    wtrans<<<dim3(16,16), tb, 0, stream>>>(Wo, WoT);

    gemm_phi_mfma<<<dim3(8, 128), tb, 0, stream>>>(Xqb, WqT, Pj, QPb);
    gemm_phi_mfma<<<dim3(8, 128), tb, 0, stream>>>(Xsb, WkT, Pj, KPb);
    gemm_mfma_bf16<<<dim3(8, 128), tb, 0, stream>>>(Xsb, WvT, Vb);

    kvs_part_kernel<<<dim3(B_*H_, 8), tb, 0, stream>>>(KPb, Vb, KVSP);
    kvs_reduce_kernel<<<B_*H_, tb, 0, stream>>>(KVSP, KVSt);

    numden_mfma<<<dim3(B_*H_, L_/128), tb, 0, stream>>>(QPb, KVSt, ATT);

    gemm_mfma_f32<<<dim3(8, 128), tb, 0, stream>>>(ATT, WoT, out);
    (void)in_sizes; (void)n_in; (void)out_size; (void)ws_size;
}